// Round 15
// baseline (129.262 us; speedup 1.0000x reference)
//
#include <hip/hip_runtime.h>
#include <hip/hip_bf16.h>

// Grouped masked GEMM (DeepSeekMOE up/gate + down), fp32 in/out, bf16 MFMA.
// G=8, M=32. up/gate: K=4096,N=2816. down: K=1408,N=4096. out: [G,32,5632] f32.
//
// R14 = R13 frontier (111-113us: 1-wave 16KB units, W gload_lds BK=128 =
// 512B row-visits, source-XOR swizzle, per-iter vmcnt(0), sequential unit
// order, XCD-affine, bf16 X in d_ws) + split-K up-units: each up unit -> two
// 16-iter K-halves accumulated via f32 atomicAdd (2 addends, deterministic).
// Balances per-block work (16 vs 11 iters) so the end-of-kernel phase keeps
// >=5 waves/CU instead of the 2.75-wave ups-only tail. d_out pre-zeroed via
// hipMemsetAsync; masked rows never stored (memset supplies the zeros).

#define G_    8
#define M_    32
#define KUG   4096
#define NUG   2816
#define KDN   1408
#define NDN   4096
#define NOUT  (NUG + NDN)      // 5632
#define BN    32
#define BK    128
#define UPT   (NUG / BN)       // 88 up units per group
#define DNT   (NDN / BN)       // 128 down units per group
#define UPH   (2 * UPT)        // 176 up half-units per group
#define UPG   (UPH + DNT)      // 304 block-units per group; grid = 2432
#define XUG_E (G_ * M_ * KUG)  // 1048576
#define XDN_E (G_ * M_ * KDN)  // 360448
#define XBF_BYTES ((size_t)(XUG_E + XDN_E) * 2)

typedef __attribute__((ext_vector_type(8))) short bf16x8;
typedef __attribute__((ext_vector_type(4))) float f32x4;

typedef __attribute__((address_space(3))) float        lds_f32;
typedef const __attribute__((address_space(1))) float  gbl_f32;

// fp32 -> bf16 RNE via compiler (m240: don't hand-write cvt_pk asm).
__device__ __forceinline__ short f2bf(float x) {
  union { __hip_bfloat16 h; short s; } u;
  u.h = __hip_bfloat16(x);
  return u.s;
}
__device__ __forceinline__ bf16x8 cvt8(f32x4 lo, f32x4 hi) {
  bf16x8 o;
#pragma unroll
  for (int j = 0; j < 4; ++j) { o[j] = f2bf(lo[j]); o[4 + j] = f2bf(hi[j]); }
  return o;
}

// Prologue: f32 -> bf16 for both X arrays, one launch (688 blocks).
__global__ void cvt_x_kernel(const float* __restrict__ xu, const float* __restrict__ xd,
                             short* __restrict__ du, short* __restrict__ dd) {
  int i = blockIdx.x * 256 + threadIdx.x;
  const float* s; short* d;
  int j = i;
  if (i < XUG_E / 8) { s = xu; d = du; }
  else { s = xd; d = dd; j = i - XUG_E / 8; if (j >= XDN_E / 8) return; }
  f32x4 lo = *(const f32x4*)(s + (size_t)j * 8);
  f32x4 hi = *(const f32x4*)(s + (size_t)j * 8 + 4);
  *(bf16x8*)(d + (size_t)j * 8) = cvt8(lo, hi);
}

// Stage W tile [32 rows][BK=128 f32] via 16 gload_lds; instr i covers rows
// {2i,2i+1}, 512B contiguous per row (measured DRAM-visit optimum). LDS dest
// linear (gload_lds rule); bank-swizzle by source-granule XOR:
// LDS[row][q] = glob[row][q ^ (row&7)] (involution, re-applied on read).
__device__ __forceinline__ void stageW(const float* wg, float* wbuf, int K,
                                       int k0, int t) {
#pragma unroll
  for (int i = 0; i < 16; ++i) {
    int gid = i * 64 + t;
    int row = gid >> 5;           // 32 granules (16B) per row
    int q   = gid & 31;
    int qs  = q ^ (row & 7);
    __builtin_amdgcn_global_load_lds(
        (gbl_f32*)(wg + (size_t)row * K + k0 + qs * 4),
        (lds_f32*)(wbuf + gid * 4), 16, 0, 0);
  }
}

// Shared inner loop: NIT iterations starting at kbase. bf16 X from xq.
__device__ __forceinline__ void gemm_loop(const float* wg, const short* xq, int K,
                                          int kbase, int NIT, float* wbuf, int t,
                                          f32x4 (&acc)[2][2]) {
  int r = t & 15, q4 = t >> 4, sk = r & 7;
  for (int it = 0; it < NIT; ++it) {
    int k0 = kbase + it * BK;
    stageW(wg, wbuf, K, k0, t);

    bf16x8 xb[2][4];              // [m-frag][k-step]
#pragma unroll
    for (int mf = 0; mf < 2; ++mf)
#pragma unroll
      for (int ks = 0; ks < 4; ++ks)
        xb[mf][ks] = *(const bf16x8*)(xq + (size_t)(mf * 16 + r) * K +
                                      k0 + ks * 32 + q4 * 8);

    // gload_lds -> ds_read dep is invisible to the compiler (rule #18).
    asm volatile("s_waitcnt vmcnt(0)" ::: "memory");
    __builtin_amdgcn_sched_barrier(0);

#pragma unroll
    for (int ks = 0; ks < 4; ++ks) {
      int g0 = (ks * 4 + q4) * 2;
      int o0 = ((g0 ^ sk) << 2), o1 = (((g0 + 1) ^ sk) << 2);
#pragma unroll
      for (int nf = 0; nf < 2; ++nf) {
        const float* rowp = wbuf + (size_t)(nf * 16 + r) * BK;
        bf16x8 bb = cvt8(*(const f32x4*)(rowp + o0), *(const f32x4*)(rowp + o1));
        acc[0][nf] = __builtin_amdgcn_mfma_f32_16x16x32_bf16(xb[0][ks], bb, acc[0][nf], 0, 0, 0);
        acc[1][nf] = __builtin_amdgcn_mfma_f32_16x16x32_bf16(xb[1][ks], bb, acc[1][nf], 0, 0, 0);
      }
    }
  }
}

__global__ __launch_bounds__(64, 2) void moe_masked_gemm(
    const float* __restrict__ w_ug, const float* __restrict__ w_dn,
    const short* __restrict__ xbf_ug, const short* __restrict__ xbf_dn,
    const int* __restrict__ masked_m, float* __restrict__ out) {
  __shared__ float wbuf[BN * BK];   // 16 KB; 2432 blocks -> ~9.5/CU, all resident

  int b = blockIdx.x;
  int g = b & 7;                    // group -> XCD affinity
  int v = b >> 3;                   // SEQUENTIAL order: up-halves then downs
                                    // (R12 A/B: interleaving costs ~28us)
  int mm = masked_m[g];
  if (mm == 0) return;              // outputs pre-zeroed by memset

  int t = threadIdx.x;
  int r = t & 15, q4 = t >> 4;

  f32x4 acc[2][2];                  // [m-frag][n-frag]
#pragma unroll
  for (int mf = 0; mf < 2; ++mf)
#pragma unroll
    for (int nf = 0; nf < 2; ++nf) acc[mf][nf] = (f32x4){0.f, 0.f, 0.f, 0.f};

  if (v < UPH) {
    // ---- up half-unit: unit u, K-half h. Pair (u,0),(u,1) covers the same
    // contiguous 512KB W panel (locality preserved); 16 iters each.
    int u = v >> 1, h = v & 1;
    int n0 = u * BN;
    const float* wg = w_ug + ((size_t)g * NUG + n0) * KUG;
    const short* xq = xbf_ug + (size_t)g * M_ * KUG;
    gemm_loop(wg, xq, KUG, h * (KUG / 2), KUG / 2 / BK, wbuf, t, acc);

    // Epilogue: accumulate (2 addends per element, f32 add commutative ->
    // deterministic). C/D layout: col = lane&15, row = (lane>>4)*4+i (m89).
    float* outg = out + (size_t)g * M_ * NOUT + n0;
#pragma unroll
    for (int i = 0; i < 4; ++i) {
      int m0 = q4 * 4 + i, m1 = 16 + m0;
#pragma unroll
      for (int nf = 0; nf < 2; ++nf) {
        if (m0 < mm) atomicAdd(&outg[(size_t)m0 * NOUT + nf * 16 + r], acc[0][nf][i]);
        if (m1 < mm) atomicAdd(&outg[(size_t)m1 * NOUT + nf * 16 + r], acc[1][nf][i]);
      }
    }
  } else {
    // ---- down unit: unchanged R13 path (11 iters), plain masked stores.
    int d = v - UPH;
    int n0 = d * BN;
    const float* wg = w_dn + ((size_t)g * NDN + n0) * KDN;
    const short* xq = xbf_dn + (size_t)g * M_ * KDN;
    gemm_loop(wg, xq, KDN, 0, KDN / BK, wbuf, t, acc);

    float* outg = out + (size_t)g * M_ * NOUT + NUG + n0;
#pragma unroll
    for (int i = 0; i < 4; ++i) {
      int m0 = q4 * 4 + i, m1 = 16 + m0;
#pragma unroll
      for (int nf = 0; nf < 2; ++nf) {
        if (m0 < mm) outg[(size_t)m0 * NOUT + nf * 16 + r] = acc[0][nf][i];
        if (m1 < mm) outg[(size_t)m1 * NOUT + nf * 16 + r] = acc[1][nf][i];
      }
    }
  }
}

// Fallback (tiny ws): R13's f32-X single-pass kernel, writes all outputs.
#define UPG2  (UPT + DNT)
__global__ __launch_bounds__(64, 2) void moe_masked_gemm_f32(
    const float* __restrict__ x_ug, const float* __restrict__ w_ug,
    const float* __restrict__ x_dn, const float* __restrict__ w_dn,
    const int* __restrict__ masked_m, float* __restrict__ out) {
  __shared__ float wbuf[BN * BK];
  int b = blockIdx.x, g = b & 7, u = b >> 3;
  const float* wg; const float* xf;
  int K, NIT, n0, colOff;
  bool is_up = (u < UPT);
  if (is_up) { K = KUG; NIT = KUG / BK; n0 = u * BN; colOff = 0;
    wg = w_ug + ((size_t)g * NUG + n0) * KUG; xf = x_ug + (size_t)g * M_ * KUG;
  } else { int d = u - UPT; K = KDN; NIT = KDN / BK; n0 = d * BN; colOff = NUG;
    wg = w_dn + ((size_t)g * NDN + n0) * KDN; xf = x_dn + (size_t)g * M_ * KDN; }
  int mm = masked_m[g], t = threadIdx.x, r = t & 15, q4 = t >> 4, sk = r & 7;
  f32x4 acc[2][2];
#pragma unroll
  for (int mf = 0; mf < 2; ++mf)
#pragma unroll
    for (int nf = 0; nf < 2; ++nf) acc[mf][nf] = (f32x4){0.f, 0.f, 0.f, 0.f};
  if (mm != 0) {
    for (int it = 0; it < NIT; ++it) {
      int k0 = it * BK;
      stageW(wg, wbuf, K, k0, t);
      bf16x8 xb[2][4];
#pragma unroll
      for (int mf = 0; mf < 2; ++mf)
#pragma unroll
        for (int ks = 0; ks < 4; ++ks) {
          const float* xp = xf + (size_t)(mf * 16 + r) * K + k0 + ks * 32 + q4 * 8;
          xb[mf][ks] = cvt8(*(const f32x4*)xp, *(const f32x4*)(xp + 4));
        }
      asm volatile("s_waitcnt vmcnt(0)" ::: "memory");
      __builtin_amdgcn_sched_barrier(0);
#pragma unroll
      for (int ks = 0; ks < 4; ++ks) {
        int g0 = (ks * 4 + q4) * 2;
        int o0 = ((g0 ^ sk) << 2), o1 = (((g0 + 1) ^ sk) << 2);
#pragma unroll
        for (int nf = 0; nf < 2; ++nf) {
          const float* rowp = wbuf + (size_t)(nf * 16 + r) * BK;
          bf16x8 bb = cvt8(*(const f32x4*)(rowp + o0), *(const f32x4*)(rowp + o1));
          acc[0][nf] = __builtin_amdgcn_mfma_f32_16x16x32_bf16(xb[0][ks], bb, acc[0][nf], 0, 0, 0);
          acc[1][nf] = __builtin_amdgcn_mfma_f32_16x16x32_bf16(xb[1][ks], bb, acc[1][nf], 0, 0, 0);
        }
      }
    }
  }
  float* outg = out + (size_t)g * M_ * NOUT + colOff + n0;
#pragma unroll
  for (int i = 0; i < 4; ++i) {
    int m0 = q4 * 4 + i, m1 = 16 + m0;
    bool v0 = m0 < mm, v1 = m1 < mm;
#pragma unroll
    for (int nf = 0; nf < 2; ++nf) {
      outg[(size_t)m0 * NOUT + nf * 16 + r] = v0 ? acc[0][nf][i] : 0.f;
      outg[(size_t)m1 * NOUT + nf * 16 + r] = v1 ? acc[1][nf][i] : 0.f;
    }
  }
}

extern "C" void kernel_launch(void* const* d_in, const int* in_sizes, int n_in,
                              void* d_out, int out_size, void* d_ws, size_t ws_size,
                              hipStream_t stream) {
  const float* x_ug     = (const float*)d_in[0];
  const float* w_ug     = (const float*)d_in[1];
  const float* x_dn     = (const float*)d_in[2];
  const float* w_dn     = (const float*)d_in[3];
  const int*   masked_m = (const int*)d_in[4];
  float*       out      = (float*)d_out;

  short* xbf_ug = (short*)d_ws;
  short* xbf_dn = xbf_ug + XUG_E;

  if (ws_size >= XBF_BYTES) {
    hipMemsetAsync(out, 0, (size_t)out_size * sizeof(float), stream);
    int n8 = (XUG_E + XDN_E) / 8;
    cvt_x_kernel<<<dim3((n8 + 255) / 256), dim3(256), 0, stream>>>(
        x_ug, x_dn, xbf_ug, xbf_dn);
    moe_masked_gemm<<<dim3(G_ * UPG), dim3(64), 0, stream>>>(
        w_ug, w_dn, xbf_ug, xbf_dn, masked_m, out);
  } else {
    moe_masked_gemm_f32<<<dim3(G_ * UPG2), dim3(64), 0, stream>>>(
        x_ug, w_ug, x_dn, w_dn, masked_m, out);
  }
}

// Round 16
// 114.128 us; speedup vs baseline: 1.1326x; 1.1326x over previous
//
#include <hip/hip_runtime.h>
#include <hip/hip_bf16.h>

// Grouped masked GEMM (DeepSeekMOE up/gate + down), fp32 in/out, bf16 MFMA.
// G=8, M=32. up/gate: K=4096,N=2816. down: K=1408,N=4096. out: [G,32,5632] f32.
//
// R15 = R13/R10 frontier, byte-exact (reproduced 111.1 / 113.4 us; kernel
// ~106-108us = 84-86% of the 6.3 TB/s achievable HBM read ceiling).
// Structure (each choice A/B-validated over 15 rounds):
//  * 1728 one-wave blocks, 16KB LDS units, 6.75 waves/CU, ALL co-resident;
//    no barriers, no cross-wave coupling (R0/R11: any coupling costs 10-30us).
//  * W staged via global_load_lds, BK=128 -> 512B contiguous per W row per
//    DMA (measured DRAM-visit optimum: 128B=147us, 256B=133, 512B=123,
//    1KB=142-152 twice).
//  * Sequential unit order (ups then downs per group): consecutive blocks
//    stream adjacent W panels -> DRAM page + L2 locality (interleaving costs
//    ~28us, R12 A/B; split-K rebalance costs ~16us, R14).
//  * Per-iter vmcnt(0) drain (counted-vmcnt/pinned pipelines: neutral-to-worse,
//    R2/R7); source-granule XOR swizzle for conflict-free ds_read_b128.
//  * X pre-converted to bf16 in d_ws (halves X fabric traffic, -12us, R10 A/B);
//    X re-reads are L2/L3-served (5.5MB working set).
//  * XCD-affine g = b&7; mm==0 groups skip all reads.

#define G_    8
#define M_    32
#define KUG   4096
#define NUG   2816
#define KDN   1408
#define NDN   4096
#define NOUT  (NUG + NDN)      // 5632
#define BN    32
#define BK    128
#define UPT   (NUG / BN)       // 88 up units per group
#define DNT   (NDN / BN)       // 128 down units per group
#define UPG   (UPT + DNT)      // 216 units per group; grid = 1728
#define XUG_E (G_ * M_ * KUG)  // 1048576
#define XDN_E (G_ * M_ * KDN)  // 360448
#define XBF_BYTES ((size_t)(XUG_E + XDN_E) * 2)

typedef __attribute__((ext_vector_type(8))) short bf16x8;
typedef __attribute__((ext_vector_type(4))) float f32x4;

typedef __attribute__((address_space(3))) float        lds_f32;
typedef const __attribute__((address_space(1))) float  gbl_f32;

// fp32 -> bf16 RNE via compiler (m240: don't hand-write cvt_pk asm).
__device__ __forceinline__ short f2bf(float x) {
  union { __hip_bfloat16 h; short s; } u;
  u.h = __hip_bfloat16(x);
  return u.s;
}
__device__ __forceinline__ bf16x8 cvt8(f32x4 lo, f32x4 hi) {
  bf16x8 o;
#pragma unroll
  for (int j = 0; j < 4; ++j) { o[j] = f2bf(lo[j]); o[4 + j] = f2bf(hi[j]); }
  return o;
}

// Prologue: f32 -> bf16 for both X arrays, one launch (688 blocks).
__global__ void cvt_x_kernel(const float* __restrict__ xu, const float* __restrict__ xd,
                             short* __restrict__ du, short* __restrict__ dd) {
  int i = blockIdx.x * 256 + threadIdx.x;
  const float* s; short* d;
  int j = i;
  if (i < XUG_E / 8) { s = xu; d = du; }
  else { s = xd; d = dd; j = i - XUG_E / 8; if (j >= XDN_E / 8) return; }
  f32x4 lo = *(const f32x4*)(s + (size_t)j * 8);
  f32x4 hi = *(const f32x4*)(s + (size_t)j * 8 + 4);
  *(bf16x8*)(d + (size_t)j * 8) = cvt8(lo, hi);
}

// Stage W tile [32 rows][BK=128 f32] via 16 gload_lds; instr i covers rows
// {2i,2i+1}, 512B contiguous per row (measured DRAM-visit optimum). LDS dest
// linear (gload_lds rule); bank-swizzle by source-granule XOR:
// LDS[row][q] = glob[row][q ^ (row&7)] (involution, re-applied on read).
__device__ __forceinline__ void stageW(const float* wg, float* wbuf, int K,
                                       int k0, int t) {
#pragma unroll
  for (int i = 0; i < 16; ++i) {
    int gid = i * 64 + t;
    int row = gid >> 5;           // 32 granules (16B) per row
    int q   = gid & 31;
    int qs  = q ^ (row & 7);
    __builtin_amdgcn_global_load_lds(
        (gbl_f32*)(wg + (size_t)row * K + k0 + qs * 4),
        (lds_f32*)(wbuf + gid * 4), 16, 0, 0);
  }
}

template<bool XBF>
__global__ __launch_bounds__(64, 2) void moe_masked_gemm(
    const float* __restrict__ x_ug, const float* __restrict__ w_ug,
    const float* __restrict__ x_dn, const float* __restrict__ w_dn,
    const short* __restrict__ xbf_ug, const short* __restrict__ xbf_dn,
    const int* __restrict__ masked_m, float* __restrict__ out) {
  __shared__ float wbuf[BN * BK];   // 16 KB -> all 1728 blocks co-resident

  int b = blockIdx.x;
  int g = b & 7;                    // group -> XCD affinity
  int u = b >> 3;                   // SEQUENTIAL unit order: [0,88) up, [88,216) down

  const float* wg;
  const float* xf;
  const short* xq;
  int K, NIT, n0, colOff;
  bool is_up = (u < UPT);
  if (is_up) {
    K = KUG; NIT = KUG / BK; n0 = u * BN; colOff = 0;          // 32 iters
    wg = w_ug + ((size_t)g * NUG + n0) * KUG;
    xf = x_ug + (size_t)g * M_ * KUG;
    xq = xbf_ug + (size_t)g * M_ * KUG;
  } else {
    int d = u - UPT;
    K = KDN; NIT = KDN / BK; n0 = d * BN; colOff = NUG;        // 11 iters
    wg = w_dn + ((size_t)g * NDN + n0) * KDN;
    xf = x_dn + (size_t)g * M_ * KDN;
    xq = xbf_dn + (size_t)g * M_ * KDN;
  }

  int mm = masked_m[g];
  int t  = threadIdx.x;
  int r  = t & 15, q4 = t >> 4;     // frag coords
  int sk = r & 7;                   // read-side swizzle key (== row&7 for lane's rows)

  f32x4 acc[2][2];                  // [m-frag][n-frag]
#pragma unroll
  for (int mf = 0; mf < 2; ++mf)
#pragma unroll
    for (int nf = 0; nf < 2; ++nf) acc[mf][nf] = (f32x4){0.f, 0.f, 0.f, 0.f};

  if (mm != 0) {                    // mm==0: skip ALL reads, epilogue writes zeros
    for (int it = 0; it < NIT; ++it) {
      int k0 = it * BK;

      // Issue the W DMAs first, then X loads ride behind them.
      stageW(wg, wbuf, K, k0, t);

      // X fragments (L2/L3-served). bf16 path: one 16B load, MFMA layout.
      bf16x8 xb[2][4];              // [m-frag][k-step]
      if constexpr (XBF) {
#pragma unroll
        for (int mf = 0; mf < 2; ++mf)
#pragma unroll
          for (int ks = 0; ks < 4; ++ks)
            xb[mf][ks] = *(const bf16x8*)(xq + (size_t)(mf * 16 + r) * K +
                                          k0 + ks * 32 + q4 * 8);
      } else {
#pragma unroll
        for (int mf = 0; mf < 2; ++mf)
#pragma unroll
          for (int ks = 0; ks < 4; ++ks) {
            const float* xp = xf + (size_t)(mf * 16 + r) * K + k0 + ks * 32 + q4 * 8;
            xb[mf][ks] = cvt8(*(const f32x4*)xp, *(const f32x4*)(xp + 4));
          }
      }

      // gload_lds -> ds_read dep is invisible to the compiler (rule #18).
      asm volatile("s_waitcnt vmcnt(0)" ::: "memory");
      __builtin_amdgcn_sched_barrier(0);

      // 4 k-steps x (2 m-frags x 2 n-frags) = 16 MFMA, swizzle-corrected reads.
#pragma unroll
      for (int ks = 0; ks < 4; ++ks) {
        int g0 = (ks * 4 + q4) * 2;
        int o0 = ((g0 ^ sk) << 2), o1 = (((g0 + 1) ^ sk) << 2);
#pragma unroll
        for (int nf = 0; nf < 2; ++nf) {
          const float* rowp = wbuf + (size_t)(nf * 16 + r) * BK;
          bf16x8 bb = cvt8(*(const f32x4*)(rowp + o0), *(const f32x4*)(rowp + o1));
          acc[0][nf] = __builtin_amdgcn_mfma_f32_16x16x32_bf16(xb[0][ks], bb, acc[0][nf], 0, 0, 0);
          acc[1][nf] = __builtin_amdgcn_mfma_f32_16x16x32_bf16(xb[1][ks], bb, acc[1][nf], 0, 0, 0);
        }
      }
      // Next iter's gload_lds can't pass this iter's ds_reads (same LDS buffer,
      // in-order wave) — validated single-buffer reuse.
    }
  }

  // Epilogue. C/D layout: col = lane&15, row = (lane>>4)*4 + i (m89-verified).
  // Lane stores cols n0 + nf*16 + r for rows m = mf*16 + q4*4 + i; mask m >= mm.
  float* outg = out + (size_t)g * M_ * NOUT + colOff + n0;
#pragma unroll
  for (int i = 0; i < 4; ++i) {
    int m0 = q4 * 4 + i, m1 = 16 + m0;
    bool v0 = m0 < mm, v1 = m1 < mm;
#pragma unroll
    for (int nf = 0; nf < 2; ++nf) {
      outg[(size_t)m0 * NOUT + nf * 16 + r] = v0 ? acc[0][nf][i] : 0.f;
      outg[(size_t)m1 * NOUT + nf * 16 + r] = v1 ? acc[1][nf][i] : 0.f;
    }
  }
}

extern "C" void kernel_launch(void* const* d_in, const int* in_sizes, int n_in,
                              void* d_out, int out_size, void* d_ws, size_t ws_size,
                              hipStream_t stream) {
  const float* x_ug     = (const float*)d_in[0];
  const float* w_ug     = (const float*)d_in[1];
  const float* x_dn     = (const float*)d_in[2];
  const float* w_dn     = (const float*)d_in[3];
  const int*   masked_m = (const int*)d_in[4];
  float*       out      = (float*)d_out;

  short* xbf_ug = (short*)d_ws;
  short* xbf_dn = xbf_ug + XUG_E;

  if (ws_size >= XBF_BYTES) {
    int n8 = (XUG_E + XDN_E) / 8;
    cvt_x_kernel<<<dim3((n8 + 255) / 256), dim3(256), 0, stream>>>(
        x_ug, x_dn, xbf_ug, xbf_dn);
    moe_masked_gemm<true><<<dim3(G_ * UPG), dim3(64), 0, stream>>>(
        x_ug, w_ug, x_dn, w_dn, xbf_ug, xbf_dn, masked_m, out);
  } else {
    moe_masked_gemm<false><<<dim3(G_ * UPG), dim3(64), 0, stream>>>(
        x_ug, w_ug, x_dn, w_dn, xbf_ug, xbf_dn, masked_m, out);
  }
}